// Round 2
// baseline (248.345 us; speedup 1.0000x reference)
//
#include <hip/hip_runtime.h>

typedef unsigned short u16;
typedef unsigned int   u32;
typedef unsigned long long u64;

typedef __bf16 bf16x8 __attribute__((ext_vector_type(8)));
typedef float  f32x4  __attribute__((ext_vector_type(4)));

#define MFMA_BF16(a,b,c) __builtin_amdgcn_mfma_f32_16x16x32_bf16((a),(b),(c),0,0,0)

__device__ __forceinline__ float bf2f(u16 u) {
    return __uint_as_float(((u32)u) << 16);
}
__device__ __forceinline__ u16 f2bf(float x) {
    u32 u = __float_as_uint(x);
    u += 0x7fffu + ((u >> 16) & 1u);   // round-to-nearest-even
    return (u16)(u >> 16);
}
// dual-dtype scalar load: f32 != 0 -> fp32 array, else bf16 array
__device__ __forceinline__ float ldany(const void* p, size_t i, int f32) {
    return f32 ? ((const float*)p)[i] : bf2f(((const u16*)p)[i]);
}

// ---------------- KD: detect float dtype of h (fp32 vs packed bf16) ------
// fp32 N(0,1): u32 exponent field in ~[117,129]. bf16-pairs read as u32:
// exponent field = low 7 bits of bf16 exponent <<1 | mantissa msb ->
// {0..5} U {248..255}. Vote over 256 words.
__global__ __launch_bounds__(256) void kdet(const u32* __restrict__ hw, int* __restrict__ flag) {
    int t = threadIdx.x;
    u32 w = hw[t];
    int e = (w >> 23) & 0xFF;
    int plausible = (e >= 64 && e <= 190) ? 1 : 0;
    u64 m = __ballot(plausible);
    __shared__ int partial[4];
    if ((t & 63) == 0) partial[t >> 6] = __popcll(m);
    __syncthreads();
    if (t == 0) flag[0] = (partial[0] + partial[1] + partial[2] + partial[3] >= 128) ? 1 : 0;
}

// ---------------- K0a: WT[n][k] = W[k][n]  (256x256 -> bf16) -------------
__global__ __launch_bounds__(256) void k0a(const void* __restrict__ w, u16* __restrict__ wt,
                                           const int* __restrict__ flag) {
    int f32 = *flag;
    int idx = blockIdx.x * 256 + threadIdx.x;
    for (int p = 0; p < 4; p++) {
        int e = idx + p * 16384;          // 65536 elements
        int k = e >> 8, n = e & 255;
        wt[n * 256 + k] = f2bf(ldany(w, e, f32));
    }
}

// ---------------- K0b: Wa1[f] = sum_o W[f][o]*a[o], Wa2 with a[256+o] ----
__global__ __launch_bounds__(256) void k0b(const void* __restrict__ w, const void* __restrict__ a,
                                           float* __restrict__ wa1, float* __restrict__ wa2,
                                           const int* __restrict__ flag) {
    int f32 = *flag;
    int f = threadIdx.x;
    float s1 = 0.f, s2 = 0.f;
    for (int o = 0; o < 256; o++) {
        float wv = ldany(w, f * 256 + o, f32);
        s1 += wv * ldany(a, o, f32);
        s2 += wv * ldany(a, 256 + o, f32);
    }
    wa1[f] = s1;
    wa2[f] = s2;
}

// ---------------- K1a: s_i[row] = h[row]·Wa1, s_j[row] = h[row]·Wa2 ------
__global__ __launch_bounds__(256) void k1a(const void* __restrict__ h,
                                           const float* __restrict__ wa1, const float* __restrict__ wa2,
                                           float* __restrict__ si, float* __restrict__ sj,
                                           const int* __restrict__ flag) {
    int f32 = *flag;
    int row = blockIdx.x * 4 + (threadIdx.x >> 6);
    int lane = threadIdx.x & 63;
    size_t base = (size_t)row * 256;
    float a1 = 0.f, a2 = 0.f;
    for (int p = 0; p < 4; p++) {
        int f = lane + p * 64;
        float hv = ldany(h, base + f, f32);
        a1 += hv * wa1[f];
        a2 += hv * wa2[f];
    }
    for (int d = 32; d; d >>= 1) { a1 += __shfl_down(a1, d); a2 += __shfl_down(a2, d); }
    if (lane == 0) { si[row] = a1; sj[row] = a2; }
}

// ---------------- K1b: mask bitset: bit(i,j) = adj[i][j]>0 || i==j -------
__global__ __launch_bounds__(256) void k1b(const int* __restrict__ adj, u64* __restrict__ mb64) {
    int wid  = blockIdx.x * 4 + (threadIdx.x >> 6);  // 1024 waves
    int lane = threadIdx.x & 63;
    for (int v = 0; v < 64; v++) {
        int idx = wid + v * 1024;                    // 65536 u64 words
        int row = idx >> 5, c64 = idx & 31;
        int j = c64 * 64 + lane;
        bool bit = (adj[(size_t)row * 2048 + j] > 0) || (j == row);
        u64 m = __ballot(bit);
        if (lane == 0) mb64[(size_t)row * 32 + c64] = m;
    }
}

// ---------------- K2: Whb_t[b][f][n] = bf16( (h@W)[b][n][f] ) ------------
struct __align__(16) K2LDS {
    u16 At[64 * 72];    // h tile   [row][k]  pad +8
    u16 Bt[256 * 72];   // WT tile  [f][k]    pad +8
};
__global__ __launch_bounds__(256) void k2(const void* __restrict__ h, const u16* __restrict__ wt,
                                          u16* __restrict__ whbt, const int* __restrict__ flag) {
    __shared__ K2LDS L;
    int f32 = *flag;
    int m0 = blockIdx.x * 64;        // global h-row
    int b  = m0 >> 11;
    int n0 = m0 & 2047;
    int t = threadIdx.x;
    int wid = t >> 6, lane = t & 63, ln = lane & 15, qd = lane >> 4;

    f32x4 acc[4][4];
    for (int mi = 0; mi < 4; mi++)
        for (int ni = 0; ni < 4; ni++)
            acc[mi][ni] = (f32x4){0.f, 0.f, 0.f, 0.f};

    for (int c = 0; c < 4; c++) {
        int k0 = c * 64;
        // stage A: 64 rows x 64 k
        for (int p = 0; p < 2; p++) {
            int r = (t >> 3) + p * 32, s = t & 7;
            if (f32) {
                const float* src = (const float*)h + (size_t)(m0 + r) * 256 + k0 + s * 8;
                f32x4 x0 = *(const f32x4*)src;
                f32x4 x1 = *(const f32x4*)(src + 4);
                u16 v[8];
                for (int q = 0; q < 4; q++) { v[q] = f2bf(x0[q]); v[4 + q] = f2bf(x1[q]); }
                *(uint4*)&L.At[r * 72 + s * 8] = *(uint4*)v;
            } else {
                *(uint4*)&L.At[r * 72 + s * 8] =
                    *(const uint4*)((const u16*)h + (size_t)(m0 + r) * 256 + k0 + s * 8);
            }
        }
        // stage B: 256 rows x 64 k (WT is ours, always bf16)
        for (int p = 0; p < 8; p++) {
            int f = (t >> 3) + p * 32, s = t & 7;
            *(uint4*)&L.Bt[f * 72 + s * 8] =
                *(const uint4*)(wt + (size_t)f * 256 + k0 + s * 8);
        }
        __syncthreads();
        for (int ks = 0; ks < 2; ks++) {
            bf16x8 af[4], bfr[4];
            for (int mi = 0; mi < 4; mi++)
                af[mi] = *(const bf16x8*)&L.At[(mi * 16 + ln) * 72 + ks * 32 + qd * 8];
            for (int ni = 0; ni < 4; ni++)
                bfr[ni] = *(const bf16x8*)&L.Bt[(wid * 64 + ni * 16 + ln) * 72 + ks * 32 + qd * 8];
            for (int mi = 0; mi < 4; mi++)
                for (int ni = 0; ni < 4; ni++)
                    acc[mi][ni] = MFMA_BF16(af[mi], bfr[ni], acc[mi][ni]);
        }
        __syncthreads();
    }
    // write transposed: lane holds 4 consecutive n at fixed f -> 8B stores
    for (int mi = 0; mi < 4; mi++) {
        for (int ni = 0; ni < 4; ni++) {
            int f = wid * 64 + ni * 16 + ln;
            int n = n0 + mi * 16 + qd * 4;
            u16 v[4];
            for (int r = 0; r < 4; r++) v[r] = f2bf(acc[mi][ni][r]);
            *(uint2*)(whbt + (size_t)b * 524288 + (size_t)f * 2048 + n) = *(uint2*)v;
        }
    }
}

// ---------------- K3: row max m and 1/sum over masked exp ----------------
__global__ __launch_bounds__(256) void k3(const float* __restrict__ sig, const float* __restrict__ sjg,
                                          const u32* __restrict__ mb,
                                          float* __restrict__ mg, float* __restrict__ invlg) {
    int row  = blockIdx.x * 4 + (threadIdx.x >> 6);  // 0..16383
    int lane = threadIdx.x & 63;
    int b = row >> 11, i = row & 2047;
    float si = sig[row];
    const float* sjb = sjg + (size_t)b * 2048;
    const u32* mrow = mb + (size_t)i * 64;
    float mloc = -3.4e38f;
    for (int p = 0; p < 32; p++) {
        int j = p * 64 + lane;
        u32 w = mrow[j >> 5];
        if ((w >> (j & 31)) & 1u) {
            float x = si + sjb[j];
            float e = fmaxf(x, 0.2f * x);
            mloc = fmaxf(mloc, e);
        }
    }
    for (int d = 32; d; d >>= 1) mloc = fmaxf(mloc, __shfl_xor(mloc, d));
    float s = 0.f;
    for (int p = 0; p < 32; p++) {
        int j = p * 64 + lane;
        u32 w = mrow[j >> 5];
        if ((w >> (j & 31)) & 1u) {
            float x = si + sjb[j];
            float e = fmaxf(x, 0.2f * x);
            s += __expf(e - mloc);
        }
    }
    for (int d = 32; d; d >>= 1) s += __shfl_xor(s, d);
    if (lane == 0) { mg[row] = mloc; invlg[row] = 1.0f / s; }
}

// ---------------- K4: fused P-gen + P@Whb + ELU --------------------------
// grid 256: b = bid&7 (XCD-resident Whb[b]), i-tile = bid>>3 (64 rows)
struct __align__(16) K4LDS {
    float sj[2048];
    float sm[64], sinv[64], ssi[64];
    u32   mw[64 * 64];     // mask words per local row
    u16   Pt[64 * 72];     // P tile [row][j] pad +8
    u16   Wt[256 * 72];    // Whb_t tile [f][j] pad +8
};
__global__ __launch_bounds__(512) void k4(const float* __restrict__ sjg, const float* __restrict__ sig,
                                          const float* __restrict__ mg, const float* __restrict__ invlg,
                                          const u32* __restrict__ mb, const u16* __restrict__ whbt,
                                          void* __restrict__ out, const int* __restrict__ flag) {
    __shared__ K4LDS L;
    int f32 = *flag;
    int b  = blockIdx.x & 7;
    int i0 = (blockIdx.x >> 3) * 64;
    int t = threadIdx.x;

    for (int p = 0; p < 4; p++) L.sj[t + p * 512] = sjg[b * 2048 + t + p * 512];
    if (t < 64) {
        int row = b * 2048 + i0 + t;
        L.sm[t] = mg[row]; L.sinv[t] = invlg[row]; L.ssi[t] = sig[row];
    }
    for (int p = 0; p < 8; p++) {
        int idx = t + p * 512;                         // 4096 words
        L.mw[idx] = mb[(size_t)(i0 + (idx >> 6)) * 64 + (idx & 63)];
    }
    __syncthreads();

    int r = t >> 3, o = t & 7;                         // P-gen: row r, j-seg o*8
    float si = L.ssi[r], mm = L.sm[r];
    int wid = t >> 6, lane = t & 63, ln = lane & 15, qd = lane >> 4;
    int wm = wid & 1, wn = wid >> 1;

    f32x4 acc[2][4];
    for (int mi = 0; mi < 2; mi++)
        for (int ni = 0; ni < 4; ni++)
            acc[mi][ni] = (f32x4){0.f, 0.f, 0.f, 0.f};

    const u16* wb = whbt + (size_t)b * 524288;

    for (int c = 0; c < 32; c++) {
        int j0 = c * 64;
        // stage Whb_t chunk: 256 f-rows x 64 j
        for (int p = 0; p < 4; p++) {
            int f = (t >> 3) + p * 64, s = t & 7;
            *(uint4*)&L.Wt[f * 72 + s * 8] =
                *(const uint4*)(wb + (size_t)f * 2048 + j0 + s * 8);
        }
        // P-gen: 8 values per thread, one b128 store
        u32 w = L.mw[r * 64 + c * 2 + (o >> 2)] >> ((o & 3) * 8);
        union { u16 us[8]; uint4 v; } pk;
        #pragma unroll
        for (int k = 0; k < 8; k++) {
            float x = si + L.sj[j0 + o * 8 + k];
            float e = fmaxf(x, 0.2f * x);
            float pv = ((w >> k) & 1u) ? __expf(e - mm) : 0.f;
            pk.us[k] = f2bf(pv);
        }
        *(uint4*)&L.Pt[r * 72 + o * 8] = pk.v;
        __syncthreads();
        #pragma unroll
        for (int ks = 0; ks < 2; ks++) {
            bf16x8 af[2], bfr[4];
            for (int mi = 0; mi < 2; mi++)
                af[mi] = *(const bf16x8*)&L.Pt[(wm * 32 + mi * 16 + ln) * 72 + ks * 32 + qd * 8];
            for (int ni = 0; ni < 4; ni++)
                bfr[ni] = *(const bf16x8*)&L.Wt[(wn * 64 + ni * 16 + ln) * 72 + ks * 32 + qd * 8];
            for (int mi = 0; mi < 2; mi++)
                for (int ni = 0; ni < 4; ni++)
                    acc[mi][ni] = MFMA_BF16(af[mi], bfr[ni], acc[mi][ni]);
        }
        __syncthreads();
    }

    // epilogue: h_prime = acc/l, ELU, store (dtype per flag)
    for (int mi = 0; mi < 2; mi++) {
        int rl0 = wm * 32 + mi * 16 + qd * 4;
        for (int ni = 0; ni < 4; ni++) {
            int f = wn * 64 + ni * 16 + ln;
            for (int reg = 0; reg < 4; reg++) {
                int rl = rl0 + reg;
                float hp = acc[mi][ni][reg] * L.sinv[rl];
                float y = hp > 0.f ? hp : (__expf(hp) - 1.f);
                size_t idx = (size_t)(b * 2048 + i0 + rl) * 256 + f;
                if (f32) ((float*)out)[idx] = y;
                else     ((u16*)out)[idx]   = f2bf(y);
            }
        }
    }
}

// ---------------- launch --------------------------------------------------
extern "C" void kernel_launch(void* const* d_in, const int* in_sizes, int n_in,
                              void* d_out, int out_size, void* d_ws, size_t ws_size,
                              hipStream_t stream) {
    const void* h   = d_in[0];              // (8,2048,256) fp32 or bf16
    const int*  adj = (const int*)d_in[1];  // int32 (2048,2048)
    const void* W   = d_in[2];              // (256,256)
    const void* a   = d_in[3];              // (512,1)

    char* ws = (char*)d_ws;
    u16*   WT   = (u16*)  (ws + 0);         // 131072 B
    float* Wa1  = (float*)(ws + 131072);    // 1024
    float* Wa2  = (float*)(ws + 132096);    // 1024
    float* si   = (float*)(ws + 133120);    // 65536
    float* sj   = (float*)(ws + 198656);    // 65536
    float* mg   = (float*)(ws + 264192);    // 65536
    float* invl = (float*)(ws + 329728);    // 65536
    u32*   mb   = (u32*)  (ws + 395264);    // 524288
    u16*   whbt = (u16*)  (ws + 919552);    // 8388608
    int*   flag = (int*)  (ws + 9308160);   // 4

    kdet<<<dim3(1),  dim3(256), 0, stream>>>((const u32*)h, flag);
    k0a<<<dim3(64),  dim3(256), 0, stream>>>(W, WT, flag);
    k0b<<<dim3(1),   dim3(256), 0, stream>>>(W, a, Wa1, Wa2, flag);
    k1a<<<dim3(4096),dim3(256), 0, stream>>>(h, Wa1, Wa2, si, sj, flag);
    k1b<<<dim3(256), dim3(256), 0, stream>>>(adj, (u64*)mb);
    k2 <<<dim3(256), dim3(256), 0, stream>>>(h, WT, whbt, flag);
    k3 <<<dim3(4096),dim3(256), 0, stream>>>(si, sj, mb, mg, invl);
    k4 <<<dim3(256), dim3(512), 0, stream>>>(sj, si, mg, invl, mb, whbt, d_out, flag);
}

// Round 3
// 220.085 us; speedup vs baseline: 1.1284x; 1.1284x over previous
//
#include <hip/hip_runtime.h>

typedef unsigned short u16;
typedef unsigned int   u32;
typedef unsigned long long u64;

typedef __bf16 bf16x8 __attribute__((ext_vector_type(8)));
typedef float  f32x4  __attribute__((ext_vector_type(4)));

#define MFMA_BF16(a,b,c) __builtin_amdgcn_mfma_f32_16x16x32_bf16((a),(b),(c),0,0,0)

#define GLOAD_LDS16(g, l) __builtin_amdgcn_global_load_lds( \
    (const __attribute__((address_space(1))) void*)(g), \
    (__attribute__((address_space(3))) void*)(l), 16, 0, 0)

__device__ __forceinline__ float bf2f(u16 u) {
    return __uint_as_float(((u32)u) << 16);
}
__device__ __forceinline__ u16 f2bf(float x) {
    u32 u = __float_as_uint(x);
    u += 0x7fffu + ((u >> 16) & 1u);   // RNE
    return (u16)(u >> 16);
}
__device__ __forceinline__ float ldany(const void* p, size_t i, int f32) {
    return f32 ? ((const float*)p)[i] : bf2f(((const u16*)p)[i]);
}
// fp32-vs-bf16 detect from first 64 words of h; identical in every wave.
__device__ __forceinline__ int detect_f32(const u32* hw) {
    u32 w = hw[threadIdx.x & 63];
    int e = (w >> 23) & 0xFF;
    u64 m = __ballot(e >= 64 && e <= 190);
    return __popcll(m) >= 32 ? 1 : 0;
}

// ---------------- K0: WT transpose + Wa1/Wa2 (fused) ---------------------
__global__ __launch_bounds__(256) void k0(const void* __restrict__ w, const void* __restrict__ a,
                                          u16* __restrict__ wt, float* __restrict__ wa1,
                                          float* __restrict__ wa2, const u32* __restrict__ hw) {
    int f32 = detect_f32(hw);
    int t = threadIdx.x;
    int idx = blockIdx.x * 256 + t;
    for (int p = 0; p < 4; p++) {
        int e = idx + p * 16384;          // 65536 elements
        int k = e >> 8, n = e & 255;
        wt[n * 256 + k] = f2bf(ldany(w, e, f32));
    }
    if (blockIdx.x == 63) {               // Wa[k] = sum_o W[k][o]*a[o]
        float s1 = 0.f, s2 = 0.f;
        for (int o = 0; o < 256; o++) {
            float wv = ldany(w, t * 256 + o, f32);
            s1 += wv * ldany(a, o, f32);
            s2 += wv * ldany(a, 256 + o, f32);
        }
        wa1[t] = s1;
        wa2[t] = s2;
    }
}

// ---------------- K1: s_i/s_j + mask bitset (fused) ----------------------
__global__ __launch_bounds__(256) void k1(const void* __restrict__ h,
                                          const float* __restrict__ wa1, const float* __restrict__ wa2,
                                          const int* __restrict__ adj,
                                          float* __restrict__ si, float* __restrict__ sj,
                                          u64* __restrict__ mb64) {
    int f32 = detect_f32((const u32*)h);
    int t = threadIdx.x;
    int wv = t >> 6, lane = t & 63;
    // part A: one row per wave
    int row = blockIdx.x * 4 + wv;
    size_t base = (size_t)row * 256;
    float a1 = 0.f, a2 = 0.f;
    for (int p = 0; p < 4; p++) {
        int f = lane + p * 64;
        float hv = ldany(h, base + f, f32);
        a1 += hv * wa1[f];
        a2 += hv * wa2[f];
    }
    for (int d = 32; d; d >>= 1) { a1 += __shfl_down(a1, d); a2 += __shfl_down(a2, d); }
    if (lane == 0) { si[row] = a1; sj[row] = a2; }
    // part B: 16 u64 mask words per block, 4 per wave (independent -> ILP)
    #pragma unroll
    for (int q = 0; q < 4; q++) {
        int idx = blockIdx.x * 16 + wv * 4 + q;        // 65536 words
        int mrow = idx >> 5, c = idx & 31;
        int j = c * 64 + lane;
        bool bit = (adj[(size_t)mrow * 2048 + j] > 0) || (j == mrow);
        u64 m = __ballot(bit);
        if (lane == 0) mb64[(size_t)mrow * 32 + c] = m;
    }
}

// ---------------- K2: Whb_t[b][f][swz(n)] = bf16((h@W)^T) ----------------
// 512 blocks, 32-row tiles. Output j-chunks swizzled: chunk' = chunk ^ (f&7).
struct __align__(16) K2LDS {
    u16 At[32 * 68];    // h tile  [row][k]  stride 68 (<=2-way banks)
    u16 Bt[256 * 68];   // WT tile [f][k]
};
__global__ __launch_bounds__(256, 2) void k2(const void* __restrict__ h, const u16* __restrict__ wt,
                                             u16* __restrict__ whbt) {
    __shared__ K2LDS L;
    int f32 = detect_f32((const u32*)h);
    int m0 = blockIdx.x * 32;
    int b  = m0 >> 11;
    int n0 = m0 & 2047;
    int t = threadIdx.x;
    int wid = t >> 6, lane = t & 63, ln = lane & 15, qd = lane >> 4;

    f32x4 acc[2][4];
    for (int mi = 0; mi < 2; mi++)
        for (int ni = 0; ni < 4; ni++)
            acc[mi][ni] = (f32x4){0.f, 0.f, 0.f, 0.f};

    for (int c = 0; c < 4; c++) {
        int k0 = c * 64;
        // stage A: 32 rows x 64 k, one 16B unit per thread
        {
            int r = t >> 3, s = t & 7;
            if (f32) {
                const float* src = (const float*)h + (size_t)(m0 + r) * 256 + k0 + s * 8;
                f32x4 x0 = *(const f32x4*)src;
                f32x4 x1 = *(const f32x4*)(src + 4);
                u16 v[8];
                for (int q = 0; q < 4; q++) { v[q] = f2bf(x0[q]); v[4 + q] = f2bf(x1[q]); }
                *(uint4*)&L.At[r * 68 + s * 8] = *(uint4*)v;
            } else {
                *(uint4*)&L.At[r * 68 + s * 8] =
                    *(const uint4*)((const u16*)h + (size_t)(m0 + r) * 256 + k0 + s * 8);
            }
        }
        // stage B: 256 f-rows x 64 k
        for (int p = 0; p < 8; p++) {
            int f = (t >> 3) + p * 32, s = t & 7;
            *(uint4*)&L.Bt[f * 68 + s * 8] =
                *(const uint4*)(wt + (size_t)f * 256 + k0 + s * 8);
        }
        __syncthreads();
        for (int ks = 0; ks < 2; ks++) {
            bf16x8 af[2], bfr[4];
            for (int mi = 0; mi < 2; mi++)
                af[mi] = *(const bf16x8*)&L.At[(mi * 16 + ln) * 68 + ks * 32 + qd * 8];
            for (int ni = 0; ni < 4; ni++)
                bfr[ni] = *(const bf16x8*)&L.Bt[(wid * 64 + ni * 16 + ln) * 68 + ks * 32 + qd * 8];
            for (int mi = 0; mi < 2; mi++)
                for (int ni = 0; ni < 4; ni++)
                    acc[mi][ni] = MFMA_BF16(af[mi], bfr[ni], acc[mi][ni]);
        }
        __syncthreads();
    }
    // write transposed + chunk-swizzled: uint2 = 4 consecutive n at fixed f
    for (int mi = 0; mi < 2; mi++) {
        for (int ni = 0; ni < 4; ni++) {
            int f = wid * 64 + ni * 16 + ln;
            int n = n0 + mi * 16 + qd * 4;
            int ns = (n & ~63) | ((((n >> 3) ^ f) & 7) << 3) | (n & 7);
            u16 v[4];
            for (int r = 0; r < 4; r++) v[r] = f2bf(acc[mi][ni][r]);
            *(uint2*)(whbt + (size_t)b * 524288 + (size_t)f * 2048 + ns) = *(uint2*)v;
        }
    }
}

// ---------------- K3: row max m and 1/sum over masked exp ----------------
__global__ __launch_bounds__(256) void k3(const float* __restrict__ sig, const float* __restrict__ sjg,
                                          const u32* __restrict__ mb,
                                          float* __restrict__ mg, float* __restrict__ invlg) {
    int row  = blockIdx.x * 4 + (threadIdx.x >> 6);
    int lane = threadIdx.x & 63;
    int b = row >> 11, i = row & 2047;
    float si = sig[row];
    const float* sjb = sjg + (size_t)b * 2048;
    const u32* mrow = mb + (size_t)i * 64;
    float mloc = -3.4e38f;
    for (int p = 0; p < 32; p++) {
        int j = p * 64 + lane;
        u32 w = mrow[j >> 5];
        if ((w >> (j & 31)) & 1u) {
            float x = si + sjb[j];
            float e = fmaxf(x, 0.2f * x);
            mloc = fmaxf(mloc, e);
        }
    }
    for (int d = 32; d; d >>= 1) mloc = fmaxf(mloc, __shfl_xor(mloc, d));
    float s = 0.f;
    for (int p = 0; p < 32; p++) {
        int j = p * 64 + lane;
        u32 w = mrow[j >> 5];
        if ((w >> (j & 31)) & 1u) {
            float x = si + sjb[j];
            float e = fmaxf(x, 0.2f * x);
            s += __expf(e - mloc);
        }
    }
    for (int d = 32; d; d >>= 1) s += __shfl_xor(s, d);
    if (lane == 0) { mg[row] = mloc; invlg[row] = 1.0f / s; }
}

// ---------------- K4: pipelined P-gen + DMA + P@Whb + ELU ----------------
// 512 blocks: b = bid&7, f-half = (bid>>3)&1, i-tile = bid>>4 (64 rows).
// One barrier per K-iter; DMA+Pgen(c+1) overlap MFMA(c). 2 blocks/CU.
struct __align__(16) K4LDS {
    float sj[2048];                    // 8192 B
    float sm[64], sinv[64], ssi[64];   // 768 B
    u64   mw[64 * 33];                 // 16896 B (stride 33: bank spread)
    u16   Pt[2][8 * 64 * 8];           // 2 x 8192 B, chunk-major [c][r][8]
    u16   Wt[2][128 * 64];             // 2 x 16384 B, [f_loc][64 j] (swz baked)
};
__global__ __launch_bounds__(256, 2) void k4(const float* __restrict__ sjg, const float* __restrict__ sig,
                                             const float* __restrict__ mg, const float* __restrict__ invlg,
                                             const u64* __restrict__ mb64, const u16* __restrict__ whbt,
                                             void* __restrict__ out, const void* __restrict__ hdet) {
    __shared__ K4LDS L;
    int f32 = detect_f32((const u32*)hdet);
    int b  = blockIdx.x & 7;
    int fh = (blockIdx.x >> 3) & 1;
    int i0 = (blockIdx.x >> 4) * 64;
    int t = threadIdx.x;
    int wid = t >> 6, lane = t & 63, ln = lane & 15, qd = lane >> 4;
    int wm = wid & 1, wn = wid >> 1;
    const u16* wb = whbt + (size_t)b * 524288 + (size_t)fh * 128 * 2048;

    // ---- DMA issue for iter c into buf: 4 x 1KB per wave -------------
    #define ISSUE_DMA(cc, bb) do {                                          \
        int j0_ = (cc) * 64;                                                \
        _Pragma("unroll")                                                   \
        for (int q = 0; q < 4; q++) {                                       \
            int k_ = wid * 4 + q;                                           \
            int fl_ = k_ * 8 + (lane >> 3);                                 \
            const u16* g_ = wb + (size_t)fl_ * 2048 + j0_ + (lane & 7) * 8; \
            GLOAD_LDS16(g_, &L.Wt[bb][k_ * 512]);                           \
        }                                                                   \
    } while (0)

    // ---- P-gen for iter c into buf: thread t -> row t&63, 16 j -------
    #define PGEN(cc, bb) do {                                               \
        int r_ = t & 63, cp_ = t >> 6;                                      \
        float si_ = L.ssi[r_], mm_ = L.sm[r_];                              \
        u64 w_ = L.mw[r_ * 33 + (cc)] >> (cp_ * 16);                        \
        int jb_ = (cc) * 64 + cp_ * 16;                                     \
        union { u16 us[16]; uint4 v[2]; } pk_;                              \
        _Pragma("unroll")                                                   \
        for (int k = 0; k < 16; k++) {                                      \
            float x_ = si_ + L.sj[jb_ + k];                                 \
            float e_ = fmaxf(x_, 0.2f * x_);                                \
            float pv_ = ((w_ >> k) & 1u) ? __expf(e_ - mm_) : 0.f;          \
            pk_.us[k] = f2bf(pv_);                                          \
        }                                                                   \
        *(uint4*)&L.Pt[bb][((2 * cp_) * 64 + r_) * 8]     = pk_.v[0];       \
        *(uint4*)&L.Pt[bb][((2 * cp_ + 1) * 64 + r_) * 8] = pk_.v[1];       \
    } while (0)

    // ---- staging of per-row state ------------------------------------
    ISSUE_DMA(0, 0);
    for (int p = 0; p < 4; p++) L.sj[t + p * 256] = sjg[b * 2048 + t + p * 256];
    for (int p = 4; p < 8; p++) L.sj[t + p * 256] = sjg[b * 2048 + t + p * 256];
    if (t < 64) {
        int row = b * 2048 + i0 + t;
        L.sm[t] = mg[row]; L.sinv[t] = invlg[row]; L.ssi[t] = sig[row];
    }
    for (int p = 0; p < 8; p++) {
        int idx = t + p * 256;                         // 2048 u64 words
        int r = idx >> 5, c = idx & 31;
        L.mw[r * 33 + c] = mb64[(size_t)(i0 + r) * 32 + c];
    }
    __syncthreads();
    PGEN(0, 0);

    f32x4 acc[2][4];
    for (int mi = 0; mi < 2; mi++)
        for (int ni = 0; ni < 4; ni++)
            acc[mi][ni] = (f32x4){0.f, 0.f, 0.f, 0.f};

    for (int c = 0; c < 32; c++) {
        int cur = c & 1, nxt = cur ^ 1;
        __syncthreads();                 // drains DMA(cur)+Pgen(cur); MFMA(c-1) done
        if (c < 31) { ISSUE_DMA(c + 1, nxt); PGEN(c + 1, nxt); }
        #pragma unroll
        for (int ks = 0; ks < 2; ks++) {
            bf16x8 af[2], bfr[4];
            #pragma unroll
            for (int mi = 0; mi < 2; mi++)
                af[mi] = *(const bf16x8*)&L.Pt[cur][((ks * 4 + qd) * 64 + wm * 32 + mi * 16 + ln) * 8];
            #pragma unroll
            for (int ni = 0; ni < 4; ni++) {
                int fl = wn * 64 + ni * 16 + ln;
                int swc = (ks * 4 + qd) ^ (fl & 7);
                bfr[ni] = *(const bf16x8*)&L.Wt[cur][fl * 64 + swc * 8];
            }
            #pragma unroll
            for (int mi = 0; mi < 2; mi++)
                #pragma unroll
                for (int ni = 0; ni < 4; ni++)
                    acc[mi][ni] = MFMA_BF16(af[mi], bfr[ni], acc[mi][ni]);
        }
    }

    // epilogue: h_prime = acc * invl, ELU, store
    for (int mi = 0; mi < 2; mi++) {
        int rl0 = wm * 32 + mi * 16 + qd * 4;
        for (int ni = 0; ni < 4; ni++) {
            int fg = fh * 128 + wn * 64 + ni * 16 + ln;
            for (int reg = 0; reg < 4; reg++) {
                int rl = rl0 + reg;
                float hp = acc[mi][ni][reg] * L.sinv[rl];
                float y = hp > 0.f ? hp : (__expf(hp) - 1.f);
                size_t idx = (size_t)(b * 2048 + i0 + rl) * 256 + fg;
                if (f32) ((float*)out)[idx] = y;
                else     ((u16*)out)[idx]   = f2bf(y);
            }
        }
    }
    #undef ISSUE_DMA
    #undef PGEN
}

// ---------------- launch --------------------------------------------------
extern "C" void kernel_launch(void* const* d_in, const int* in_sizes, int n_in,
                              void* d_out, int out_size, void* d_ws, size_t ws_size,
                              hipStream_t stream) {
    const void* h   = d_in[0];              // (8,2048,256) fp32 or bf16
    const int*  adj = (const int*)d_in[1];  // int32 (2048,2048)
    const void* W   = d_in[2];              // (256,256)
    const void* a   = d_in[3];              // (512,1)

    char* ws = (char*)d_ws;
    u16*   WT   = (u16*)  (ws + 0);         // 131072 B
    float* Wa1  = (float*)(ws + 131072);
    float* Wa2  = (float*)(ws + 132096);
    float* si   = (float*)(ws + 133120);    // 65536
    float* sj   = (float*)(ws + 198656);    // 65536
    float* mg   = (float*)(ws + 264192);    // 65536
    float* invl = (float*)(ws + 329728);    // 65536
    u64*   mb64 = (u64*)  (ws + 395264);    // 524288
    u16*   whbt = (u16*)  (ws + 919552);    // 8388608

    k0<<<dim3(64),   dim3(256), 0, stream>>>(W, a, WT, Wa1, Wa2, (const u32*)h);
    k1<<<dim3(4096), dim3(256), 0, stream>>>(h, Wa1, Wa2, adj, si, sj, mb64);
    k2<<<dim3(512),  dim3(256), 0, stream>>>(h, WT, whbt);
    k3<<<dim3(4096), dim3(256), 0, stream>>>(si, sj, (const u32*)mb64, mg, invl);
    k4<<<dim3(512),  dim3(256), 0, stream>>>(sj, si, mg, invl, mb64, whbt, d_out, h);
}

// Round 5
// 187.135 us; speedup vs baseline: 1.3271x; 1.1761x over previous
//
#include <hip/hip_runtime.h>

typedef unsigned short u16;
typedef unsigned int   u32;
typedef unsigned long long u64;

typedef __bf16 bf16x8 __attribute__((ext_vector_type(8)));
typedef float  f32x4  __attribute__((ext_vector_type(4)));

#define MFMA_BF16(a,b,c) __builtin_amdgcn_mfma_f32_16x16x32_bf16((a),(b),(c),0,0,0)

#define GLOAD_LDS16(g, l) __builtin_amdgcn_global_load_lds( \
    (const __attribute__((address_space(1))) void*)(g), \
    (__attribute__((address_space(3))) void*)(l), 16, 0, 0)

__device__ __forceinline__ float bf2f(u16 u) {
    return __uint_as_float(((u32)u) << 16);
}
__device__ __forceinline__ u16 f2bf(float x) {
    u32 u = __float_as_uint(x);
    u += 0x7fffu + ((u >> 16) & 1u);   // RNE
    return (u16)(u >> 16);
}
__device__ __forceinline__ float ldany(const void* p, size_t i, int f32) {
    return f32 ? ((const float*)p)[i] : bf2f(((const u16*)p)[i]);
}
// fp32-vs-bf16 detect from first 64 words of h; identical in every wave.
__device__ __forceinline__ int detect_f32(const u32* hw) {
    u32 w = hw[threadIdx.x & 63];
    int e = (w >> 23) & 0xFF;
    u64 m = __ballot(e >= 64 && e <= 190);
    return __popcll(m) >= 32 ? 1 : 0;
}

// ---------------- K0: 256 blocks — WT col + Wa1/Wa2 row-reduce -----------
__global__ __launch_bounds__(256) void k0(const void* __restrict__ w, const void* __restrict__ a,
                                          u16* __restrict__ wt, float* __restrict__ wa1,
                                          float* __restrict__ wa2, const u32* __restrict__ hw) {
    int f32 = detect_f32(hw);
    int k = blockIdx.x, o = threadIdx.x;
    float wv = ldany(w, (size_t)k * 256 + o, f32);
    wt[o * 256 + k] = f2bf(wv);
    float p1 = wv * ldany(a, o, f32);
    float p2 = wv * ldany(a, 256 + o, f32);
    for (int d = 32; d; d >>= 1) { p1 += __shfl_down(p1, d); p2 += __shfl_down(p2, d); }
    __shared__ float s1[4], s2[4];
    int wid = o >> 6, lane = o & 63;
    if (lane == 0) { s1[wid] = p1; s2[wid] = p2; }
    __syncthreads();
    if (o == 0) { wa1[k] = s1[0] + s1[1] + s1[2] + s1[3]; wa2[k] = s2[0] + s2[1] + s2[2] + s2[3]; }
}

// ---------------- K1: s_i/s_j + mask bitset (fused) ----------------------
__global__ __launch_bounds__(256) void k1(const void* __restrict__ h,
                                          const float* __restrict__ wa1, const float* __restrict__ wa2,
                                          const int* __restrict__ adj,
                                          float* __restrict__ si, float* __restrict__ sj,
                                          u64* __restrict__ mb64) {
    int f32 = detect_f32((const u32*)h);
    int t = threadIdx.x;
    int wv = t >> 6, lane = t & 63;
    int row = blockIdx.x * 4 + wv;
    size_t base = (size_t)row * 256;
    float a1 = 0.f, a2 = 0.f;
    for (int p = 0; p < 4; p++) {
        int f = lane + p * 64;
        float hv = ldany(h, base + f, f32);
        a1 += hv * wa1[f];
        a2 += hv * wa2[f];
    }
    for (int d = 32; d; d >>= 1) { a1 += __shfl_down(a1, d); a2 += __shfl_down(a2, d); }
    if (lane == 0) { si[row] = a1; sj[row] = a2; }
    #pragma unroll
    for (int q = 0; q < 4; q++) {
        int idx = blockIdx.x * 16 + wv * 4 + q;        // 65536 words
        int mrow = idx >> 5, c = idx & 31;
        int j = c * 64 + lane;
        bool bit = (adj[(size_t)mrow * 2048 + j] > 0) || (j == mrow);
        u64 m = __ballot(bit);
        if (lane == 0) mb64[(size_t)mrow * 32 + c] = m;
    }
}

// ---------------- K2: Whb_t[b][f][swz(n)] = bf16((h@W)^T) ----------------
// 256 blocks, 64-row tiles. LDS-transpose epilogue -> contiguous 16B stores.
struct __align__(16) K2LDS {
    u16 At[64 * 68];
    union { u16 Bt[256 * 68]; u16 Ct[256 * 68]; };
};
__global__ __launch_bounds__(256) void k2(const void* __restrict__ h, const u16* __restrict__ wt,
                                          u16* __restrict__ whbt) {
    __shared__ K2LDS L;
    int f32 = detect_f32((const u32*)h);
    int m0 = blockIdx.x * 64;
    int b  = m0 >> 11;
    int n0 = m0 & 2047;
    int t = threadIdx.x;
    int wid = t >> 6, lane = t & 63, ln = lane & 15, qd = lane >> 4;

    f32x4 acc[4][4];
    for (int mi = 0; mi < 4; mi++)
        for (int ni = 0; ni < 4; ni++)
            acc[mi][ni] = (f32x4){0.f, 0.f, 0.f, 0.f};

    for (int c = 0; c < 4; c++) {
        int k0c = c * 64;
        for (int p = 0; p < 2; p++) {
            int r = (t >> 3) + p * 32, s = t & 7;
            if (f32) {
                const float* src = (const float*)h + (size_t)(m0 + r) * 256 + k0c + s * 8;
                f32x4 x0 = *(const f32x4*)src;
                f32x4 x1 = *(const f32x4*)(src + 4);
                u16 v[8];
                for (int q = 0; q < 4; q++) { v[q] = f2bf(x0[q]); v[4 + q] = f2bf(x1[q]); }
                *(uint4*)&L.At[r * 68 + s * 8] = *(uint4*)v;
            } else {
                *(uint4*)&L.At[r * 68 + s * 8] =
                    *(const uint4*)((const u16*)h + (size_t)(m0 + r) * 256 + k0c + s * 8);
            }
        }
        for (int p = 0; p < 8; p++) {
            int f = (t >> 3) + p * 32, s = t & 7;
            *(uint4*)&L.Bt[f * 68 + s * 8] =
                *(const uint4*)(wt + (size_t)f * 256 + k0c + s * 8);
        }
        __syncthreads();
        for (int ks = 0; ks < 2; ks++) {
            bf16x8 af[4], bfr[4];
            for (int mi = 0; mi < 4; mi++)
                af[mi] = *(const bf16x8*)&L.At[(mi * 16 + ln) * 68 + ks * 32 + qd * 8];
            for (int ni = 0; ni < 4; ni++)
                bfr[ni] = *(const bf16x8*)&L.Bt[(wid * 64 + ni * 16 + ln) * 68 + ks * 32 + qd * 8];
            for (int mi = 0; mi < 4; mi++)
                for (int ni = 0; ni < 4; ni++)
                    acc[mi][ni] = MFMA_BF16(af[mi], bfr[ni], acc[mi][ni]);
        }
        __syncthreads();
    }
    // transpose via LDS: Ct[f][n-local], then contiguous global writes
    for (int mi = 0; mi < 4; mi++) {
        for (int ni = 0; ni < 4; ni++) {
            int f = wid * 64 + ni * 16 + ln;
            int n = mi * 16 + qd * 4;
            u16 v[4];
            for (int r = 0; r < 4; r++) v[r] = f2bf(acc[mi][ni][r]);
            *(uint2*)&L.Ct[f * 68 + n] = *(uint2*)v;
        }
    }
    __syncthreads();
    {
        int fr = t;
        size_t base = (size_t)b * 524288 + (size_t)fr * 2048 + n0;
        #pragma unroll
        for (int s = 0; s < 8; s++) {
            int qsrc = s ^ (fr & 7);                   // global pos s holds quad s^(f&7)
            uint4 v = *(uint4*)&L.Ct[fr * 68 + qsrc * 8];
            *(uint4*)(whbt + base + s * 8) = v;
        }
    }
}

// ---------------- K3: row m,l + factored-exp tables ----------------------
__global__ __launch_bounds__(256) void k3(const float* __restrict__ sig, const float* __restrict__ sjg,
                                          const u32* __restrict__ mb,
                                          float* __restrict__ u1g, float* __restrict__ u2g,
                                          float* __restrict__ invlg,
                                          u32* __restrict__ vpackg, u16* __restrict__ sjbfg) {
    int row  = blockIdx.x * 4 + (threadIdx.x >> 6);
    int lane = threadIdx.x & 63;
    int b = row >> 11, i = row & 2047;
    float si = sig[row];
    const float* sjb = sjg + (size_t)b * 2048;
    const u32* mrow = mb + (size_t)i * 64;
    float mloc = -3.4e38f;
    for (int p = 0; p < 32; p++) {
        int j = p * 64 + lane;
        u32 w = mrow[j >> 5];
        if ((w >> (j & 31)) & 1u) {
            float x = si + sjb[j];
            float e = fmaxf(x, 0.2f * x);
            mloc = fmaxf(mloc, e);
        }
    }
    for (int d = 32; d; d >>= 1) mloc = fmaxf(mloc, __shfl_xor(mloc, d));
    float s = 0.f;
    for (int p = 0; p < 32; p++) {
        int j = p * 64 + lane;
        u32 w = mrow[j >> 5];
        if ((w >> (j & 31)) & 1u) {
            float x = si + sjb[j];
            float e = fmaxf(x, 0.2f * x);
            s += __expf(e - mloc);
        }
    }
    for (int d = 32; d; d >>= 1) s += __shfl_xor(s, d);
    if (lane == 0) {
        invlg[row] = 1.0f / s;
        u1g[row] = __expf(si - mloc);
        u2g[row] = __expf(0.2f * si - mloc);
        float sjv = sjb[i];
        float vj  = __expf(sjv);
        float v2j = __expf(0.2f * sjv);
        vpackg[row] = (u32)f2bf(vj) | ((u32)f2bf(v2j) << 16);
        sjbfg[row]  = f2bf(sjv);
    }
}

// ---------------- K4: pipelined P-gen(factored) + DMA + P@Whb + ELU ------
// 256 blocks x 512 thr: b = bid&7 (XCD-resident), i-tile = bid>>3 (64 rows),
// full 256-f per block (no P duplication). 1 block/CU, 8 waves.
struct __align__(16) K4LDS {
    u32   vpack[2048];                 // 8192 B  (bf16 vj | v2j<<16)
    u16   sjb[2048];                   // 4096 B  (bf16 s_j)
    u64   mw[64 * 33];                 // 16896 B
    float u1[64], u2[64], inv[64], nsi[64];  // 1024 B
    u16   Pt[2][4096];                 // 2 x 8192 B, [octet][row][8]
    u16   Wt[2][16384];                // 2 x 32768 B, [f][64 j] (swz baked)
};
__global__ __launch_bounds__(512, 2) void k4(const float* __restrict__ sig,
                                             const float* __restrict__ u1g, const float* __restrict__ u2g,
                                             const float* __restrict__ invlg,
                                             const u32* __restrict__ vpackg, const u16* __restrict__ sjbfg,
                                             const u64* __restrict__ mb64, const u16* __restrict__ whbt,
                                             void* __restrict__ out, const void* __restrict__ hdet) {
    __shared__ K4LDS L;
    int f32 = detect_f32((const u32*)hdet);
    int b  = blockIdx.x & 7;
    int i0 = (blockIdx.x >> 3) * 64;
    int t = threadIdx.x;
    int wid = t >> 6, lane = t & 63, ln = lane & 15, qd = lane >> 4;
    int wm = wid & 1, wn = wid >> 1;
    const u16* wb = whbt + (size_t)b * 524288;

    // DMA for iter c into buf bb: 8 waves x 4 x 1KB = 32 KB (256 f x 64 j)
    #define ISSUE_DMA(cc, bb) do {                                          \
        int j0_ = (cc) * 64;                                                \
        _Pragma("unroll")                                                   \
        for (int q = 0; q < 4; q++) {                                       \
            int k_ = wid * 4 + q;                                           \
            int fl_ = k_ * 8 + (lane >> 3);                                 \
            const u16* g_ = wb + (size_t)fl_ * 2048 + j0_ + (lane & 7) * 8; \
            GLOAD_LDS16(g_, &L.Wt[bb][k_ * 512]);                           \
        }                                                                   \
    } while (0)

    // Factored P-gen: thread -> row t&63, j-octet t>>6 (8 values, no exp).
    // Consecutive-j pairing: pair pk = columns (jb+2pk, jb+2pk+1).
    #define PGEN(cc, bb) do {                                               \
        int r_ = t & 63, o_ = t >> 6;                                       \
        int jb_ = (cc) * 64 + o_ * 8;                                       \
        uint4 pkA_ = *(const uint4*)&L.vpack[jb_];                          \
        uint4 pkB_ = *(const uint4*)&L.vpack[jb_ + 4];                      \
        uint4 sj4_ = *(const uint4*)&L.sjb[jb_];                            \
        u32 mb_ = (u32)(L.mw[r_ * 33 + (cc)] >> (o_ * 8)) & 0xffu;          \
        float u1_ = L.u1[r_], u2_ = L.u2[r_], nsi_ = L.nsi[r_];             \
        u32 pr_[4];                                                         \
        _Pragma("unroll")                                                   \
        for (int pk = 0; pk < 4; pk++) {                                    \
            u32 vw0_ = (pk == 0) ? pkA_.x : (pk == 1) ? pkA_.z              \
                     : (pk == 2) ? pkB_.x : pkB_.z;                         \
            u32 vw1_ = (pk == 0) ? pkA_.y : (pk == 1) ? pkA_.w              \
                     : (pk == 2) ? pkB_.y : pkB_.w;                         \
            u32 sw_ = (pk == 0) ? sj4_.x : (pk == 1) ? sj4_.y               \
                     : (pk == 2) ? sj4_.z : sj4_.w;                         \
            float sj0_ = __uint_as_float(sw_ << 16);                        \
            float sj1_ = __uint_as_float(sw_ & 0xffff0000u);                \
            float p0_, p1_;                                                 \
            {                                                               \
                bool pos = sj0_ > nsi_;                                     \
                float vv = __uint_as_float(pos ? (vw0_ << 16)               \
                                               : ((vw0_ >> 16) << 16));     \
                p0_ = (pos ? u1_ : u2_) * vv;                               \
                p0_ = ((mb_ >> (2 * pk)) & 1u) ? p0_ : 0.f;                 \
            }                                                               \
            {                                                               \
                bool pos = sj1_ > nsi_;                                     \
                float vv = __uint_as_float(pos ? (vw1_ << 16)               \
                                               : ((vw1_ >> 16) << 16));     \
                p1_ = (pos ? u1_ : u2_) * vv;                               \
                p1_ = ((mb_ >> (2 * pk + 1)) & 1u) ? p1_ : 0.f;             \
            }                                                               \
            pr_[pk] = __builtin_amdgcn_perm(__float_as_uint(p1_),           \
                                            __float_as_uint(p0_),           \
                                            0x07060302u);                   \
        }                                                                   \
        *(uint4*)&L.Pt[bb][(o_ * 64 + r_) * 8] = *(uint4*)pr_;              \
    } while (0)

    ISSUE_DMA(0, 0);
    // stage tables
    for (int p = 0; p < 4; p++) { int idx = t + p * 512; L.vpack[idx] = vpackg[b * 2048 + idx]; }
    for (int p = 0; p < 2; p++) { int idx = t + p * 512;
        ((u32*)L.sjb)[idx] = ((const u32*)(sjbfg + (size_t)b * 2048))[idx]; }
    for (int p = 0; p < 4; p++) {
        int idx = t + p * 512;                          // 2048 u64 words
        int r = idx >> 5, c = idx & 31;
        L.mw[r * 33 + c] = mb64[(size_t)(i0 + r) * 32 + c];
    }
    if (t < 64) {
        int row = b * 2048 + i0 + t;
        L.u1[t] = u1g[row]; L.u2[t] = u2g[row]; L.inv[t] = invlg[row]; L.nsi[t] = -sig[row];
    }
    __syncthreads();
    PGEN(0, 0);

    f32x4 acc[2][4];
    for (int mi = 0; mi < 2; mi++)
        for (int ni = 0; ni < 4; ni++)
            acc[mi][ni] = (f32x4){0.f, 0.f, 0.f, 0.f};

    for (int c = 0; c < 32; c++) {
        int cur = c & 1, nxt = cur ^ 1;
        __syncthreads();                 // drains DMA(cur)+Pgen(cur)
        if (c < 31) { ISSUE_DMA(c + 1, nxt); PGEN(c + 1, nxt); }
        #pragma unroll
        for (int ks = 0; ks < 2; ks++) {
            bf16x8 af[2], bfr[4];
            #pragma unroll
            for (int mi = 0; mi < 2; mi++)
                af[mi] = *(const bf16x8*)&L.Pt[cur][((ks * 4 + qd) * 64 + wm * 32 + mi * 16 + ln) * 8];
            #pragma unroll
            for (int ni = 0; ni < 4; ni++) {
                int fl = wn * 64 + ni * 16 + ln;
                int swc = (ks * 4 + qd) ^ (fl & 7);
                bfr[ni] = *(const bf16x8*)&L.Wt[cur][fl * 64 + swc * 8];
            }
            #pragma unroll
            for (int mi = 0; mi < 2; mi++)
                #pragma unroll
                for (int ni = 0; ni < 4; ni++)
                    acc[mi][ni] = MFMA_BF16(af[mi], bfr[ni], acc[mi][ni]);
        }
    }

    // epilogue: h_prime = acc * invl, ELU, store
    for (int mi = 0; mi < 2; mi++) {
        int rl0 = wm * 32 + mi * 16 + qd * 4;
        for (int ni = 0; ni < 4; ni++) {
            int fg = wn * 64 + ni * 16 + ln;
            for (int reg = 0; reg < 4; reg++) {
                int rl = rl0 + reg;
                float hp = acc[mi][ni][reg] * L.inv[rl];
                float y = hp > 0.f ? hp : (__expf(hp) - 1.f);
                size_t idx = (size_t)(b * 2048 + i0 + rl) * 256 + fg;
                if (f32) ((float*)out)[idx] = y;
                else     ((u16*)out)[idx]   = f2bf(y);
            }
        }
    }
    #undef ISSUE_DMA
    #undef PGEN
}

// ---------------- launch --------------------------------------------------
extern "C" void kernel_launch(void* const* d_in, const int* in_sizes, int n_in,
                              void* d_out, int out_size, void* d_ws, size_t ws_size,
                              hipStream_t stream) {
    const void* h   = d_in[0];              // (8,2048,256) fp32 (detected) or bf16
    const int*  adj = (const int*)d_in[1];  // int32 (2048,2048)
    const void* W   = d_in[2];              // (256,256)
    const void* a   = d_in[3];              // (512,1)

    char* ws = (char*)d_ws;
    u16*   WT    = (u16*)  (ws + 0);        // 131072
    float* si    = (float*)(ws + 131072);   // 65536
    float* sj    = (float*)(ws + 196608);   // 65536
    float* u1    = (float*)(ws + 262144);   // 65536
    float* u2    = (float*)(ws + 327680);   // 65536
    float* invl  = (float*)(ws + 393216);   // 65536
    u32*   vpack = (u32*)  (ws + 458752);   // 65536
    u16*   sjbf  = (u16*)  (ws + 524288);   // 32768
    u64*   mb64  = (u64*)  (ws + 557056);   // 524288
    u16*   whbt  = (u16*)  (ws + 1081344);  // 8388608 (end 9469952)
    float* Wa1   = (float*)(ws + 9469952);  // 1024
    float* Wa2   = (float*)(ws + 9470976);  // 1024

    k0<<<dim3(256),  dim3(256), 0, stream>>>(W, a, WT, Wa1, Wa2, (const u32*)h);
    k1<<<dim3(4096), dim3(256), 0, stream>>>(h, Wa1, Wa2, adj, si, sj, mb64);
    k2<<<dim3(256),  dim3(256), 0, stream>>>(h, WT, whbt);
    k3<<<dim3(4096), dim3(256), 0, stream>>>(si, sj, (const u32*)mb64, u1, u2, invl, vpack, sjbf);
    k4<<<dim3(256),  dim3(512), 0, stream>>>(si, u1, u2, invl, vpack, sjbf, mb64, whbt, d_out, h);
}

// Round 6
// 143.241 us; speedup vs baseline: 1.7338x; 1.3064x over previous
//
#include <hip/hip_runtime.h>

typedef unsigned short u16;
typedef unsigned int   u32;
typedef unsigned long long u64;

typedef __bf16 bf16x8 __attribute__((ext_vector_type(8)));
typedef float  f32x4  __attribute__((ext_vector_type(4)));

#define MFMA_BF16(a,b,c) __builtin_amdgcn_mfma_f32_16x16x32_bf16((a),(b),(c),0,0,0)

#define GLOAD_LDS16(g, l) __builtin_amdgcn_global_load_lds( \
    (const __attribute__((address_space(1))) void*)(g), \
    (__attribute__((address_space(3))) void*)(l), 16, 0, 0)

__device__ __forceinline__ float bf2f(u16 u) {
    return __uint_as_float(((u32)u) << 16);
}
__device__ __forceinline__ u16 f2bf(float x) {
    u32 u = __float_as_uint(x);
    u += 0x7fffu + ((u >> 16) & 1u);   // RNE
    return (u16)(u >> 16);
}
__device__ __forceinline__ float ldany(const void* p, size_t i, int f32) {
    return f32 ? ((const float*)p)[i] : bf2f(((const u16*)p)[i]);
}
// fp32-vs-bf16 detect from first 64 words of h; identical in every wave.
__device__ __forceinline__ int detect_f32(const u32* hw) {
    u32 w = hw[threadIdx.x & 63];
    int e = (w >> 23) & 0xFF;
    u64 m = __ballot(e >= 64 && e <= 190);
    return __popcll(m) >= 32 ? 1 : 0;
}

// ---------------- K0: 256 blocks — WT col + Wa1/Wa2 row-reduce -----------
__global__ __launch_bounds__(256) void k0(const void* __restrict__ w, const void* __restrict__ a,
                                          u16* __restrict__ wt, float* __restrict__ wa1,
                                          float* __restrict__ wa2, const u32* __restrict__ hw) {
    int f32 = detect_f32(hw);
    int k = blockIdx.x, o = threadIdx.x;
    float wv = ldany(w, (size_t)k * 256 + o, f32);
    wt[o * 256 + k] = f2bf(wv);
    float p1 = wv * ldany(a, o, f32);
    float p2 = wv * ldany(a, 256 + o, f32);
    for (int d = 32; d; d >>= 1) { p1 += __shfl_down(p1, d); p2 += __shfl_down(p2, d); }
    __shared__ float s1[4], s2[4];
    int wid = o >> 6, lane = o & 63;
    if (lane == 0) { s1[wid] = p1; s2[wid] = p2; }
    __syncthreads();
    if (o == 0) { wa1[k] = s1[0] + s1[1] + s1[2] + s1[3]; wa2[k] = s2[0] + s2[1] + s2[2] + s2[3]; }
}

// ---------------- K1: s_i/s_j + mask bitset (fused) ----------------------
__global__ __launch_bounds__(256) void k1(const void* __restrict__ h,
                                          const float* __restrict__ wa1, const float* __restrict__ wa2,
                                          const int* __restrict__ adj,
                                          float* __restrict__ si, float* __restrict__ sj,
                                          u64* __restrict__ mb64) {
    int f32 = detect_f32((const u32*)h);
    int t = threadIdx.x;
    int wv = t >> 6, lane = t & 63;
    int row = blockIdx.x * 4 + wv;
    size_t base = (size_t)row * 256;
    float a1 = 0.f, a2 = 0.f;
    for (int p = 0; p < 4; p++) {
        int f = lane + p * 64;
        float hv = ldany(h, base + f, f32);
        a1 += hv * wa1[f];
        a2 += hv * wa2[f];
    }
    for (int d = 32; d; d >>= 1) { a1 += __shfl_down(a1, d); a2 += __shfl_down(a2, d); }
    if (lane == 0) { si[row] = a1; sj[row] = a2; }
    #pragma unroll
    for (int q = 0; q < 4; q++) {
        int idx = blockIdx.x * 16 + wv * 4 + q;        // 65536 words
        int mrow = idx >> 5, c = idx & 31;
        int j = c * 64 + lane;
        bool bit = (adj[(size_t)mrow * 2048 + j] > 0) || (j == mrow);
        u64 m = __ballot(bit);
        if (lane == 0) mb64[(size_t)mrow * 32 + c] = m;
    }
}

// ---------------- K2: Whb_t[b][f][swz(n)] = bf16((h@W)^T) ----------------
// 256 blocks, 64-row tiles. LDS-transpose epilogue -> contiguous 16B stores.
struct __align__(16) K2LDS {
    u16 At[64 * 68];
    union { u16 Bt[256 * 68]; u16 Ct[256 * 68]; };
};
__global__ __launch_bounds__(256) void k2(const void* __restrict__ h, const u16* __restrict__ wt,
                                          u16* __restrict__ whbt) {
    __shared__ K2LDS L;
    int f32 = detect_f32((const u32*)h);
    int m0 = blockIdx.x * 64;
    int b  = m0 >> 11;
    int n0 = m0 & 2047;
    int t = threadIdx.x;
    int wid = t >> 6, lane = t & 63, ln = lane & 15, qd = lane >> 4;

    f32x4 acc[4][4];
    for (int mi = 0; mi < 4; mi++)
        for (int ni = 0; ni < 4; ni++)
            acc[mi][ni] = (f32x4){0.f, 0.f, 0.f, 0.f};

    for (int c = 0; c < 4; c++) {
        int k0c = c * 64;
        for (int p = 0; p < 2; p++) {
            int r = (t >> 3) + p * 32, s = t & 7;
            if (f32) {
                const float* src = (const float*)h + (size_t)(m0 + r) * 256 + k0c + s * 8;
                f32x4 x0 = *(const f32x4*)src;
                f32x4 x1 = *(const f32x4*)(src + 4);
                u16 v[8];
                for (int q = 0; q < 4; q++) { v[q] = f2bf(x0[q]); v[4 + q] = f2bf(x1[q]); }
                *(uint4*)&L.At[r * 68 + s * 8] = *(uint4*)v;
            } else {
                *(uint4*)&L.At[r * 68 + s * 8] =
                    *(const uint4*)((const u16*)h + (size_t)(m0 + r) * 256 + k0c + s * 8);
            }
        }
        for (int p = 0; p < 8; p++) {
            int f = (t >> 3) + p * 32, s = t & 7;
            *(uint4*)&L.Bt[f * 68 + s * 8] =
                *(const uint4*)(wt + (size_t)f * 256 + k0c + s * 8);
        }
        __syncthreads();
        for (int ks = 0; ks < 2; ks++) {
            bf16x8 af[4], bfr[4];
            for (int mi = 0; mi < 4; mi++)
                af[mi] = *(const bf16x8*)&L.At[(mi * 16 + ln) * 68 + ks * 32 + qd * 8];
            for (int ni = 0; ni < 4; ni++)
                bfr[ni] = *(const bf16x8*)&L.Bt[(wid * 64 + ni * 16 + ln) * 68 + ks * 32 + qd * 8];
            for (int mi = 0; mi < 4; mi++)
                for (int ni = 0; ni < 4; ni++)
                    acc[mi][ni] = MFMA_BF16(af[mi], bfr[ni], acc[mi][ni]);
        }
        __syncthreads();
    }
    // transpose via LDS: Ct[f][n-local], then contiguous global writes
    for (int mi = 0; mi < 4; mi++) {
        for (int ni = 0; ni < 4; ni++) {
            int f = wid * 64 + ni * 16 + ln;
            int n = mi * 16 + qd * 4;
            u16 v[4];
            for (int r = 0; r < 4; r++) v[r] = f2bf(acc[mi][ni][r]);
            *(uint2*)&L.Ct[f * 68 + n] = *(uint2*)v;
        }
    }
    __syncthreads();
    {
        int fr = t;
        size_t base = (size_t)b * 524288 + (size_t)fr * 2048 + n0;
        #pragma unroll
        for (int s = 0; s < 8; s++) {
            int qsrc = s ^ (fr & 7);                   // global pos s holds quad s^(f&7)
            uint4 v = *(uint4*)&L.Ct[fr * 68 + qsrc * 8];
            *(uint4*)(whbt + base + s * 8) = v;
        }
    }
}

// ---------------- K3n: per-batch shift + factored-exp tables -------------
// K_i = lrelu(s_i + Mb), Mb = max_j s_j (batch). All exps in [e^-35, 1]:
// softmax is shift-invariant; diagonal (always masked) bounds the row max
// from below within ~35, so no overflow and no total-underflow. l_i is NOT
// computed here — k4 row-sums its own P values.
__global__ __launch_bounds__(512) void k3n(const float* __restrict__ sig, const float* __restrict__ sjg,
                                           float* __restrict__ u1g, float* __restrict__ u2g,
                                           u32* __restrict__ vpackg, u16* __restrict__ sjbfg) {
    int b = blockIdx.x;           // 8 blocks, one per batch
    int t = threadIdx.x;          // 512
    const float* sjb = sjg + (size_t)b * 2048;
    float mx = -3.4e38f;
    #pragma unroll
    for (int p = 0; p < 4; p++) mx = fmaxf(mx, sjb[t + p * 512]);
    for (int d = 32; d; d >>= 1) mx = fmaxf(mx, __shfl_xor(mx, d));
    __shared__ float wmax[8];
    int wid = t >> 6, lane = t & 63;
    if (lane == 0) wmax[wid] = mx;
    __syncthreads();
    float Mb = fmaxf(fmaxf(fmaxf(wmax[0], wmax[1]), fmaxf(wmax[2], wmax[3])),
                     fmaxf(fmaxf(wmax[4], wmax[5]), fmaxf(wmax[6], wmax[7])));
    #pragma unroll
    for (int p = 0; p < 4; p++) {
        int j = t + p * 512;
        float sjv = sjb[j];
        float vj  = __expf(sjv - Mb);            // <= 1
        float v2j = __expf(0.2f * (sjv - Mb));   // <= 1
        vpackg[b * 2048 + j] = (u32)f2bf(vj) | ((u32)f2bf(v2j) << 16);
        sjbfg[b * 2048 + j]  = f2bf(sjv);
        float siv = sig[b * 2048 + j];
        float x = siv + Mb;
        float K = fmaxf(x, 0.2f * x);            // lrelu(s_i + Mb)
        u1g[b * 2048 + j] = __expf(x - K);       // <= 1
        u2g[b * 2048 + j] = __expf(0.2f * x - K);// <= 1
    }
}

// ---------------- K4: pipelined P-gen + DMA + P@Whb + inline-l + ELU -----
// 256 blocks x 512 thr: b = bid&7 (XCD-resident), i-tile = bid>>3 (64 rows).
struct __align__(16) K4LDS {
    u32   vpack[2048];                 // 8192 B  (bf16 vj | v2j<<16)
    u16   sjb[2048];                   // 4096 B  (bf16 s_j)
    u64   mw[64 * 33];                 // 16896 B
    float u1[64], u2[64], inv[64], nsi[64];  // 1024 B
    float lred[512];                   // 2048 B  (8 partial row-sums x 64 rows)
    u16   Pt[2][4096];                 // 2 x 8192 B, [octet][row][8]
    u16   Wt[2][16384];                // 2 x 32768 B, [f][64 j] (swz baked)
};
__global__ __launch_bounds__(512, 2) void k4(const float* __restrict__ sig,
                                             const float* __restrict__ u1g, const float* __restrict__ u2g,
                                             const u32* __restrict__ vpackg, const u16* __restrict__ sjbfg,
                                             const u64* __restrict__ mb64, const u16* __restrict__ whbt,
                                             void* __restrict__ out, const void* __restrict__ hdet) {
    __shared__ K4LDS L;
    int f32 = detect_f32((const u32*)hdet);
    int b  = blockIdx.x & 7;
    int i0 = (blockIdx.x >> 3) * 64;
    int t = threadIdx.x;
    int wid = t >> 6, lane = t & 63, ln = lane & 15, qd = lane >> 4;
    int wm = wid & 1, wn = wid >> 1;
    const u16* wb = whbt + (size_t)b * 524288;
    float lacc = 0.f;                  // running row-partial of P (fp32)

    // DMA for iter c into buf bb: 8 waves x 4 x 1KB = 32 KB (256 f x 64 j)
    #define ISSUE_DMA(cc, bb) do {                                          \
        int j0_ = (cc) * 64;                                                \
        _Pragma("unroll")                                                   \
        for (int q = 0; q < 4; q++) {                                       \
            int k_ = wid * 4 + q;                                           \
            int fl_ = k_ * 8 + (lane >> 3);                                 \
            const u16* g_ = wb + (size_t)fl_ * 2048 + j0_ + (lane & 7) * 8; \
            GLOAD_LDS16(g_, &L.Wt[bb][k_ * 512]);                           \
        }                                                                   \
    } while (0)

    // Factored P-gen: thread -> row t&63, j-octet t>>6; accumulates lacc.
    #define PGEN(cc, bb) do {                                               \
        int r_ = t & 63, o_ = t >> 6;                                       \
        int jb_ = (cc) * 64 + o_ * 8;                                       \
        uint4 pkA_ = *(const uint4*)&L.vpack[jb_];                          \
        uint4 pkB_ = *(const uint4*)&L.vpack[jb_ + 4];                      \
        uint4 sj4_ = *(const uint4*)&L.sjb[jb_];                            \
        u32 mb_ = (u32)(L.mw[r_ * 33 + (cc)] >> (o_ * 8)) & 0xffu;          \
        float u1_ = L.u1[r_], u2_ = L.u2[r_], nsi_ = L.nsi[r_];             \
        u32 pr_[4];                                                         \
        _Pragma("unroll")                                                   \
        for (int pk = 0; pk < 4; pk++) {                                    \
            u32 vw0_ = (pk == 0) ? pkA_.x : (pk == 1) ? pkA_.z              \
                     : (pk == 2) ? pkB_.x : pkB_.z;                         \
            u32 vw1_ = (pk == 0) ? pkA_.y : (pk == 1) ? pkA_.w              \
                     : (pk == 2) ? pkB_.y : pkB_.w;                         \
            u32 sw_ = (pk == 0) ? sj4_.x : (pk == 1) ? sj4_.y               \
                     : (pk == 2) ? sj4_.z : sj4_.w;                         \
            float sj0_ = __uint_as_float(sw_ << 16);                        \
            float sj1_ = __uint_as_float(sw_ & 0xffff0000u);                \
            float p0_, p1_;                                                 \
            {                                                               \
                bool pos = sj0_ > nsi_;                                     \
                float vv = __uint_as_float(pos ? (vw0_ << 16)               \
                                               : ((vw0_ >> 16) << 16));     \
                p0_ = (pos ? u1_ : u2_) * vv;                               \
                p0_ = ((mb_ >> (2 * pk)) & 1u) ? p0_ : 0.f;                 \
            }                                                               \
            {                                                               \
                bool pos = sj1_ > nsi_;                                     \
                float vv = __uint_as_float(pos ? (vw1_ << 16)               \
                                               : ((vw1_ >> 16) << 16));     \
                p1_ = (pos ? u1_ : u2_) * vv;                               \
                p1_ = ((mb_ >> (2 * pk + 1)) & 1u) ? p1_ : 0.f;             \
            }                                                               \
            lacc += p0_ + p1_;                                              \
            pr_[pk] = __builtin_amdgcn_perm(__float_as_uint(p1_),           \
                                            __float_as_uint(p0_),           \
                                            0x07060302u);                   \
        }                                                                   \
        *(uint4*)&L.Pt[bb][(o_ * 64 + r_) * 8] = *(uint4*)pr_;              \
    } while (0)

    ISSUE_DMA(0, 0);
    // stage tables
    for (int p = 0; p < 4; p++) { int idx = t + p * 512; L.vpack[idx] = vpackg[b * 2048 + idx]; }
    for (int p = 0; p < 2; p++) { int idx = t + p * 512;
        ((u32*)L.sjb)[idx] = ((const u32*)(sjbfg + (size_t)b * 2048))[idx]; }
    for (int p = 0; p < 4; p++) {
        int idx = t + p * 512;                          // 2048 u64 words
        int r = idx >> 5, c = idx & 31;
        L.mw[r * 33 + c] = mb64[(size_t)(i0 + r) * 32 + c];
    }
    if (t < 64) {
        int row = b * 2048 + i0 + t;
        L.u1[t] = u1g[row]; L.u2[t] = u2g[row]; L.nsi[t] = -sig[row];
    }
    __syncthreads();
    PGEN(0, 0);

    f32x4 acc[2][4];
    for (int mi = 0; mi < 2; mi++)
        for (int ni = 0; ni < 4; ni++)
            acc[mi][ni] = (f32x4){0.f, 0.f, 0.f, 0.f};

    for (int c = 0; c < 32; c++) {
        int cur = c & 1, nxt = cur ^ 1;
        __syncthreads();                 // drains DMA(cur)+Pgen(cur)
        if (c < 31) { ISSUE_DMA(c + 1, nxt); PGEN(c + 1, nxt); }
        #pragma unroll
        for (int ks = 0; ks < 2; ks++) {
            bf16x8 af[2], bfr[4];
            #pragma unroll
            for (int mi = 0; mi < 2; mi++)
                af[mi] = *(const bf16x8*)&L.Pt[cur][((ks * 4 + qd) * 64 + wm * 32 + mi * 16 + ln) * 8];
            #pragma unroll
            for (int ni = 0; ni < 4; ni++) {
                int fl = wn * 64 + ni * 16 + ln;
                int swc = (ks * 4 + qd) ^ (fl & 7);
                bfr[ni] = *(const bf16x8*)&L.Wt[cur][fl * 64 + swc * 8];
            }
            #pragma unroll
            for (int mi = 0; mi < 2; mi++)
                #pragma unroll
                for (int ni = 0; ni < 4; ni++)
                    acc[mi][ni] = MFMA_BF16(af[mi], bfr[ni], acc[mi][ni]);
        }
    }

    // reduce row sums l_i: 8 partials per row (thread t holds row t&63)
    __syncthreads();
    L.lred[t] = lacc;                    // t = o_*64 + r_ layout
    __syncthreads();
    if (t < 64) {
        float s = 0.f;
        #pragma unroll
        for (int q = 0; q < 8; q++) s += L.lred[q * 64 + t];
        L.inv[t] = 1.0f / s;
    }
    __syncthreads();

    // epilogue: h_prime = acc * inv_l, ELU, store
    for (int mi = 0; mi < 2; mi++) {
        int rl0 = wm * 32 + mi * 16 + qd * 4;
        for (int ni = 0; ni < 4; ni++) {
            int fg = wn * 64 + ni * 16 + ln;
            for (int reg = 0; reg < 4; reg++) {
                int rl = rl0 + reg;
                float hp = acc[mi][ni][reg] * L.inv[rl];
                float y = hp > 0.f ? hp : (__expf(hp) - 1.f);
                size_t idx = (size_t)(b * 2048 + i0 + rl) * 256 + fg;
                if (f32) ((float*)out)[idx] = y;
                else     ((u16*)out)[idx]   = f2bf(y);
            }
        }
    }
    #undef ISSUE_DMA
    #undef PGEN
}

// ---------------- launch --------------------------------------------------
extern "C" void kernel_launch(void* const* d_in, const int* in_sizes, int n_in,
                              void* d_out, int out_size, void* d_ws, size_t ws_size,
                              hipStream_t stream) {
    const void* h   = d_in[0];              // (8,2048,256) fp32 (detected) or bf16
    const int*  adj = (const int*)d_in[1];  // int32 (2048,2048)
    const void* W   = d_in[2];              // (256,256)
    const void* a   = d_in[3];              // (512,1)

    char* ws = (char*)d_ws;
    u16*   WT    = (u16*)  (ws + 0);        // 131072
    float* si    = (float*)(ws + 131072);   // 65536
    float* sj    = (float*)(ws + 196608);   // 65536
    float* u1    = (float*)(ws + 262144);   // 65536
    float* u2    = (float*)(ws + 327680);   // 65536
    u32*   vpack = (u32*)  (ws + 458752);   // 65536
    u16*   sjbf  = (u16*)  (ws + 524288);   // 32768
    u64*   mb64  = (u64*)  (ws + 557056);   // 524288
    u16*   whbt  = (u16*)  (ws + 1081344);  // 8388608 (end 9469952)
    float* Wa1   = (float*)(ws + 9469952);  // 1024
    float* Wa2   = (float*)(ws + 9470976);  // 1024

    k0 <<<dim3(256),  dim3(256), 0, stream>>>(W, a, WT, Wa1, Wa2, (const u32*)h);
    k1 <<<dim3(4096), dim3(256), 0, stream>>>(h, Wa1, Wa2, adj, si, sj, mb64);
    k2 <<<dim3(256),  dim3(256), 0, stream>>>(h, WT, whbt);
    k3n<<<dim3(8),    dim3(512), 0, stream>>>(si, sj, u1, u2, vpack, sjbf);
    k4 <<<dim3(256),  dim3(512), 0, stream>>>(si, u1, u2, vpack, sjbf, mb64, whbt, d_out, h);
}